// Round 1
// baseline (119.772 us; speedup 1.0000x reference)
//
#include <hip/hip_runtime.h>
#include <hip/hip_bf16.h>

#define B_ 2
#define N_ 512
#define D_ 64
#define H_ 128
#define OUT_ 64

using bf16x8 = __attribute__((ext_vector_type(8))) __bf16;
using f32x4  = __attribute__((ext_vector_type(4))) float;

// ws layout (bytes):
//   xa_b1 : float[B*N*H]          @ 0        (524288)
//   xb    : float[B*N*H]          @ 524288   (524288)
//   w2t   : bf16 [H*H]            @ 1048576  (32768)
//   S     : float[B*H]            @ 1081344  (1024)

__global__ __launch_bounds__(256) void prep_kernel(
    const float* __restrict__ x, const float* __restrict__ W1,
    const float* __restrict__ b1, const float* __restrict__ W2,
    float* __restrict__ xa, float* __restrict__ xb,
    __hip_bfloat16* __restrict__ w2t, float* __restrict__ S)
{
    int idx = blockIdx.x * 256 + threadIdx.x;
    if (idx < B_ * N_ * H_) {
        int h  = idx & (H_ - 1);
        int bn = idx >> 7;                 // b*N + n
        const float* xr = x + bn * D_;
        float aa = 0.f, ab = 0.f;
        #pragma unroll
        for (int k = 0; k < D_; k++) {
            float xv = xr[k];
            aa += xv * W1[k * H_ + h];
            ab += xv * W1[(k + D_) * H_ + h];
        }
        xa[idx] = aa + b1[h];              // fold b1 into xa
        xb[idx] = ab;
    }
    if (idx < H_ * H_) {                   // W2 transposed, bf16
        int k = idx & (H_ - 1);
        int n = idx >> 7;
        w2t[n * H_ + k] = __float2bfloat16(W2[k * H_ + n]);
    }
    if (idx < B_ * H_) S[idx] = 0.f;
}

// Block: 256 threads (4 waves). Tile: 64 i's x 16 j's. Wave w handles i's
// [i0+16w, i0+16w+16), each i is one 16-row MFMA tile (rows = 16 j's).
// W2^T fragments live in VGPRs for the whole block (reused 64x).
__global__ __launch_bounds__(256, 2) void pair_kernel(
    const float* __restrict__ xa, const float* __restrict__ xb,
    const uint4* __restrict__ w2t, const float* __restrict__ b2,
    float* __restrict__ S)
{
    const int tid  = threadIdx.x;
    const int lane = tid & 63;
    const int wid  = tid >> 6;
    const int l15  = lane & 15;
    const int quad = lane >> 4;

    const int j0 = blockIdx.x * 16;
    const int i0 = blockIdx.y * 64;
    const int b  = blockIdx.z;

    // B fragments: bfrag[c][s] = W2^T[16c+l15][32s + 8*quad .. +8]
    bf16x8 bfrag[8][4];
    #pragma unroll
    for (int c = 0; c < 8; c++) {
        int row = 16 * c + l15;
        #pragma unroll
        for (int s = 0; s < 4; s++) {
            union { uint4 u; bf16x8 v; } cv;
            cv.u = w2t[row * 16 + s * 4 + quad];
            bfrag[c][s] = cv.v;
        }
    }

    // xa(+b1) for this block's 16 j's: per lane 32 floats (k = 32s+8quad+t)
    const float* xaB = xa + (size_t)(b * N_ + j0 + l15) * H_;
    f32x4 av[4][2];
    #pragma unroll
    for (int s = 0; s < 4; s++) {
        const f32x4* p = (const f32x4*)(xaB + s * 32 + quad * 8);
        av[s][0] = p[0];
        av[s][1] = p[1];
    }

    float b2v[8];
    #pragma unroll
    for (int c = 0; c < 8; c++) b2v[c] = b2[16 * c + l15];

    float csum[8];
    #pragma unroll
    for (int c = 0; c < 8; c++) csum[c] = 0.f;

    const float* xbB = xb + (size_t)(b * N_) * H_;

    for (int r = 0; r < 16; r++) {
        const int i = i0 + wid * 16 + r;
        const float* xr = xbB + i * H_;

        // A fragments: relu(xa[j0+l15] + xb[i] (+b1)) -> bf16
        bf16x8 afr[4];
        #pragma unroll
        for (int s = 0; s < 4; s++) {
            const f32x4* p = (const f32x4*)(xr + s * 32 + quad * 8);
            f32x4 u0 = p[0], u1 = p[1];
            f32x4 v0 = av[s][0], v1 = av[s][1];
            bf16x8 a;
            #pragma unroll
            for (int t = 0; t < 4; t++) {
                float f0 = v0[t] + u0[t]; f0 = f0 > 0.f ? f0 : 0.f;
                float f1 = v1[t] + u1[t]; f1 = f1 > 0.f ? f1 : 0.f;
                a[t]     = (__bf16)f0;
                a[t + 4] = (__bf16)f1;
            }
            afr[s] = a;
        }

        #pragma unroll
        for (int c = 0; c < 8; c++) {
            f32x4 acc = {0.f, 0.f, 0.f, 0.f};
            #pragma unroll
            for (int s = 0; s < 4; s++)
                acc = __builtin_amdgcn_mfma_f32_16x16x32_bf16(afr[s], bfrag[c][s], acc, 0, 0, 0);
            // relu(acc + b2), sum the 4 rows this lane holds
            float t0 = acc[0] + b2v[c]; t0 = t0 > 0.f ? t0 : 0.f;
            float t1 = acc[1] + b2v[c]; t1 = t1 > 0.f ? t1 : 0.f;
            float t2 = acc[2] + b2v[c]; t2 = t2 > 0.f ? t2 : 0.f;
            float t3 = acc[3] + b2v[c]; t3 = t3 > 0.f ? t3 : 0.f;
            csum[c] += t0 + t1 + t2 + t3;
        }
    }

    // cross-quad reduction: every lane ends with full column sum for col 16c+l15
    #pragma unroll
    for (int c = 0; c < 8; c++) {
        float v = csum[c];
        v += __shfl_xor(v, 16, 64);
        v += __shfl_xor(v, 32, 64);
        csum[c] = v;
    }

    __shared__ float sred[4][H_];
    if (lane < 16) {
        #pragma unroll
        for (int c = 0; c < 8; c++) sred[wid][c * 16 + l15] = csum[c];
    }
    __syncthreads();
    if (tid < H_) {
        float tot = sred[0][tid] + sred[1][tid] + sred[2][tid] + sred[3][tid];
        atomicAdd(&S[b * H_ + tid], tot);
    }
}

__global__ __launch_bounds__(128) void tail_kernel(
    const float* __restrict__ S, const float* __restrict__ W3,
    const float* __restrict__ b3, const float* __restrict__ V1,
    const float* __restrict__ c1, const float* __restrict__ V2,
    const float* __restrict__ c2, float* __restrict__ out)
{
    __shared__ float pool[H_], ov[H_];
    const int b = blockIdx.x, t = threadIdx.x;
    const float* Sb = S + b * H_;
    float acc = 0.f;
    for (int k = 0; k < H_; k++) acc += Sb[k] * W3[k * H_ + t];
    pool[t] = acc + (float)(N_ * N_) * b3[t];
    __syncthreads();
    acc = c1[t];
    for (int k = 0; k < H_; k++) acc += pool[k] * V1[k * H_ + t];
    ov[t] = acc > 0.f ? acc : 0.f;
    __syncthreads();
    if (t < OUT_) {
        acc = c2[t];
        for (int k = 0; k < H_; k++) acc += ov[k] * V2[k * OUT_ + t];
        out[b * OUT_ + t] = acc;
    }
}

extern "C" void kernel_launch(void* const* d_in, const int* in_sizes, int n_in,
                              void* d_out, int out_size, void* d_ws, size_t ws_size,
                              hipStream_t stream) {
    const float* x  = (const float*)d_in[0];
    const float* W1 = (const float*)d_in[1];
    const float* b1 = (const float*)d_in[2];
    const float* W2 = (const float*)d_in[3];
    const float* b2 = (const float*)d_in[4];
    const float* W3 = (const float*)d_in[5];
    const float* b3 = (const float*)d_in[6];
    const float* V1 = (const float*)d_in[7];
    const float* c1 = (const float*)d_in[8];
    const float* V2 = (const float*)d_in[9];
    const float* c2 = (const float*)d_in[10];
    float* out = (float*)d_out;

    char* ws = (char*)d_ws;
    float*          xa  = (float*)(ws);
    float*          xb  = (float*)(ws + 524288);
    __hip_bfloat16* w2t = (__hip_bfloat16*)(ws + 1048576);
    float*          S   = (float*)(ws + 1048576 + 32768);

    prep_kernel<<<512, 256, 0, stream>>>(x, W1, b1, W2, xa, xb, w2t, S);
    dim3 g2(N_ / 16, N_ / 64, B_);
    pair_kernel<<<g2, 256, 0, stream>>>(xa, xb, (const uint4*)w2t, b2, S);
    tail_kernel<<<B_, 128, 0, stream>>>(S, W3, b3, V1, c1, V2, c2, out);
}